// Round 13
// baseline (404.397 us; speedup 1.0000x reference)
//
#include <hip/hip_runtime.h>
#include <hip/hip_bf16.h>

#define B_  16
#define S_  4096
#define DIN 512
#define DH  512

typedef _Float16 f16x8 __attribute__((ext_vector_type(8)));
typedef float    f32x4 __attribute__((ext_vector_type(4)));

// ---------------- ws layout (bytes) ----------------
// W16     : [DH][DIN] fp16      @ 0        (524288)
// addv    : [B_][DH]  f32       @ 524288   (32768)   = input@W_in.T + b_in + b_ctx
// scores  : [B_][S_]  f32       @ 557056   (262144)  pure-store by score (no zeroing)
// wsum    : [B_][DIN] f32       @ 819200   (32768)   zeroed in prep, atomicAdd by attnwsum
// maskflag: int                 @ 851968   (4)

__device__ __forceinline__ float fast_tanh(float x) {
    float e = __expf(2.f * x);
    return 1.f - 2.f * __builtin_amdgcn_rcpf(e + 1.f);
}

__device__ __forceinline__ int mask_at(const void* mask, int isByte, int idx) {
    return isByte ? (int)((const unsigned char*)mask)[idx]
                  : ((const int*)mask)[idx];
}

// ---------------- prep ----------------
// grid 291:
//   [0,256)   W_ctx f32 -> f16
//   [256,288) addv = input@W_in.T + b_in + b_ctx
//   288       mask dtype detect
//   [289,291) zero wsum (8192 floats)
__global__ __launch_bounds__(256)
void prep_kernel(const float* __restrict__ input,
                 const float* __restrict__ W_in,
                 const float* __restrict__ b_in,
                 const float* __restrict__ W_ctx,
                 const float* __restrict__ b_ctx,
                 const void*  __restrict__ mask,
                 _Float16* __restrict__ W16,
                 float* __restrict__ addv,
                 float* __restrict__ wsum,
                 int* __restrict__ maskflag) {
    int blk = blockIdx.x;
    int tid = threadIdx.x;
    if (blk < 256) {
        int base = blk * 1024 + tid * 4;
        float4 wv = *(const float4*)(W_ctx + base);
        union { _Float16 f[4]; ushort4 u; } cv;
        cv.f[0] = (_Float16)wv.x; cv.f[1] = (_Float16)wv.y;
        cv.f[2] = (_Float16)wv.z; cv.f[3] = (_Float16)wv.w;
        *(ushort4*)(W16 + base) = cv.u;
    } else if (blk < 288) {
        int t = blk - 256;
        int b = t >> 1;
        int h = ((t & 1) << 8) + tid;
        __shared__ float inrow[DIN];
        inrow[tid]       = input[b * DIN + tid];
        inrow[tid + 256] = input[b * DIN + tid + 256];
        __syncthreads();
        const float* wr = W_in + (size_t)h * DIN;
        float acc = 0.f;
        for (int k = 0; k < DIN; k += 4) {
            float4 w4 = *(const float4*)(wr + k);
            acc += w4.x * inrow[k] + w4.y * inrow[k + 1]
                 + w4.z * inrow[k + 2] + w4.w * inrow[k + 3];
        }
        addv[b * DH + h] = acc + b_in[h] + b_ctx[h];
    } else if (blk == 288) {
        const uint4* m4 = (const uint4*)mask;
        unsigned int orw = 0;
#pragma unroll
        for (int it = 0; it < 16; ++it) {
            uint4 w = m4[it * 256 + tid];
            orw |= (w.x | w.y | w.z | w.w);
        }
        int found = ((orw & 0xFFFFFF00u) != 0) ? 1 : 0;
        __shared__ int f;
        if (tid == 0) f = 0;
        __syncthreads();
        if (found) atomicOr(&f, 1);
        __syncthreads();
        if (tid == 0) maskflag[0] = f;
    } else {
        int base = (blk - 289) * 4096;
#pragma unroll
        for (int it = 0; it < 16; ++it)
            wsum[base + it * 256 + tid] = 0.f;
    }
}

// ---------------- score GEMM: scores = rowsum of v.tanh(addv + ctx@W16^T) ----
// NO-LDS / NO-BARRIER K-loop. Key identity (verified all session): both MFMA
// operand fragments use the SAME per-lane address pattern on their row-major
// source: frag(tile) lane(l15,q) = SRC[(tile*16+l15)*DIN + kc*32 + q*8 .. +8].
// r7/r8 proved it for B direct-from-global; A uses it too (the LDS staging
// identity), so A loads direct as 2x dwordx4 f32 + in-register cvt.
// => zero LDS traffic, zero __syncthreads in the loop, no vmcnt drains.
// Waves slide freely; compiler hoists next-step loads over MFMAs (no fences).
// Reuse via caches: the block's 8 waves read the same 8KB A-slice per step
// (L1-broadcast); W16 is L2-resident.
//   - 1024 blocks = 16b x 64st (64-row chunks), 512 thr / 8 waves.
//   - wave = ng: owns all 64 rows x its 64 cols -> acc[4][4] (64 VGPR).
//   - per step/wave: 8 A-loads + 4 B-loads + 16 cvt_pk + 16 MFMA.
//   - 1-deep ping-pong prefetch (named sets s0/s1, rule-#20-safe).
//   - nt=1 -> pure-store epilogue (ng LDS-reduce, ONE barrier at kernel end).
__global__ __launch_bounds__(512)
void score_kernel(const float* __restrict__ context,
                  const _Float16* __restrict__ W16,
                  const float* __restrict__ addv,
                  const float* __restrict__ v,
                  float* __restrict__ scores) {
    __shared__ float sred[8][64];

    const int tid  = threadIdx.x;
    const int ng   = tid >> 6;         // 0..7 : wave = n-group (64 cols)
    const int lane = tid & 63;
    const int l15  = lane & 15;
    const int q    = lane >> 4;

    const int b  = blockIdx.x >> 6;
    const int st = blockIdx.x & 63;
    const int s0 = st * 64;

    const float*    ctxA = context + ((size_t)b * S_ + s0) * DIN;
    const _Float16* Wn   = W16 + (size_t)(ng * 64) * DIN;

    // per-lane row bases (element offsets into the resp. matrices)
    // A frag jm: ctxA[(jm*16+l15)*DIN + kc*32 + q*8 + {0..7}]   (8 f32)
    // B frag jn: Wn  [(jn*16+l15)*DIN + kc*32 + q*8 + {0..7}]   (8 f16)
    const int rbase = l15 * DIN + q * 8;

#define LOADAB(kc_, as_, bs_)                                                  \
    {                                                                          \
        _Pragma("unroll")                                                      \
        for (int jm = 0; jm < 4; ++jm) {                                       \
            const float* g = ctxA + jm * 16 * DIN + rbase + (kc_) * 32;        \
            as_[2 * jm]     = *(const float4*)g;                               \
            as_[2 * jm + 1] = *(const float4*)(g + 4);                         \
        }                                                                      \
        _Pragma("unroll")                                                      \
        for (int jn = 0; jn < 4; ++jn)                                         \
            bs_[jn] = *(const f16x8*)(Wn + jn * 16 * DIN + rbase + (kc_) * 32);\
    }

#define CVTMFMA(as_, bs_)                                                      \
    {                                                                          \
        f16x8 afr[4];                                                          \
        _Pragma("unroll")                                                      \
        for (int jm = 0; jm < 4; ++jm) {                                       \
            f16x8 t;                                                           \
            t[0] = (_Float16)as_[2 * jm].x;  t[1] = (_Float16)as_[2 * jm].y;   \
            t[2] = (_Float16)as_[2 * jm].z;  t[3] = (_Float16)as_[2 * jm].w;   \
            t[4] = (_Float16)as_[2 * jm + 1].x; t[5] = (_Float16)as_[2 * jm + 1].y; \
            t[6] = (_Float16)as_[2 * jm + 1].z; t[7] = (_Float16)as_[2 * jm + 1].w; \
            afr[jm] = t;                                                       \
        }                                                                      \
        _Pragma("unroll")                                                      \
        for (int jn = 0; jn < 4; ++jn)                                         \
            _Pragma("unroll")                                                  \
            for (int jm = 0; jm < 4; ++jm)                                     \
                acc[jm][jn] = __builtin_amdgcn_mfma_f32_16x16x32_f16(          \
                    afr[jm], bs_[jn], acc[jm][jn], 0, 0, 0);                   \
    }

    f32x4 acc[4][4];
#pragma unroll
    for (int jm = 0; jm < 4; ++jm)
#pragma unroll
        for (int jn = 0; jn < 4; ++jn) acc[jm][jn] = (f32x4){0.f, 0.f, 0.f, 0.f};

    float4 aS0[8], aS1[8];   // A f32 ping-pong sets (named, rule-#20-safe)
    f16x8  bS0[4], bS1[4];   // B ping-pong sets

    LOADAB(0, aS0, bS0);
    for (int kp = 0; kp < 8; ++kp) {
        LOADAB(2 * kp + 1, aS1, bS1);        // prefetch odd step
        CVTMFMA(aS0, bS0);                   // consume even step
        if (kp < 7) LOADAB(2 * kp + 2, aS0, bS0);  // prefetch next even
        CVTMFMA(aS1, bS1);                   // consume odd step
    }

    // ---- epilogue: rowsum over this wave's 64 n-cols, LDS-reduce over ng ----
    const float* avb = addv + b * DH;
    float rowsum[4][4] = {{0.f,0.f,0.f,0.f},{0.f,0.f,0.f,0.f},
                          {0.f,0.f,0.f,0.f},{0.f,0.f,0.f,0.f}};
#pragma unroll
    for (int jn = 0; jn < 4; ++jn) {
        int n = ng * 64 + jn * 16 + l15;
        float av = avb[n];
        float vv = v[n];
#pragma unroll
        for (int jm = 0; jm < 4; ++jm)
#pragma unroll
            for (int r = 0; r < 4; ++r)
                rowsum[jm][r] += vv * fast_tanh(acc[jm][jn][r] + av);
    }
#pragma unroll
    for (int jm = 0; jm < 4; ++jm)
#pragma unroll
        for (int r = 0; r < 4; ++r) {
            float s = rowsum[jm][r];
            s += __shfl_xor(s, 1, 16);
            s += __shfl_xor(s, 2, 16);
            s += __shfl_xor(s, 4, 16);
            s += __shfl_xor(s, 8, 16);
            if (l15 == 0)
                sred[ng][jm * 16 + q * 4 + r] = s;   // C row = q*4+r
        }
    __syncthreads();
    if (tid < 64) {
        float out = 0.f;
#pragma unroll
        for (int w = 0; w < 8; ++w) out += sred[w][tid];
        scores[b * S_ + s0 + tid] = out;
    }
}

// ---------------- attn write + sparse weighted context sum (stats fused) ----
// r12 version: float4 gather, parity split, LDS combine.
__global__ __launch_bounds__(256)
void attnwsum_kernel(const float* __restrict__ scores,
                     const float* __restrict__ context,
                     const void* __restrict__ mask,
                     const int* __restrict__ maskflag,
                     float* __restrict__ attn,
                     float* __restrict__ wsum) {
    __shared__ float rbuf[8];
    __shared__ int   selIdx[64];
    __shared__ float selW[64];
    __shared__ int   selCount;
    __shared__ float sh[1024];          // [2 parities][512 h]

    int b  = blockIdx.x >> 6;
    int c0 = (blockIdx.x & 63) * 64;
    int tid = threadIdx.x;
    int wv = tid >> 6, ln = tid & 63;
    int isByte = maskflag[0];
    const float* sr = scores + b * S_;

    float mx = -__builtin_inff();
    float vals[16];
#pragma unroll
    for (int it = 0; it < 16; ++it) {
        int s = it * 256 + tid;
        float x = mask_at(mask, isByte, b * S_ + s) ? -__builtin_inff() : sr[s];
        vals[it] = x;
        mx = fmaxf(mx, x);
    }
    for (int o = 1; o < 64; o <<= 1) mx = fmaxf(mx, __shfl_xor(mx, o, 64));
    if (ln == 0) rbuf[wv] = mx;
    __syncthreads();
    mx = fmaxf(fmaxf(rbuf[0], rbuf[1]), fmaxf(rbuf[2], rbuf[3]));

    float sum = 0.f;
#pragma unroll
    for (int it = 0; it < 16; ++it) sum += __expf(vals[it] - mx);
    for (int o = 1; o < 64; o <<= 1) sum += __shfl_xor(sum, o, 64);
    if (ln == 0) rbuf[4 + wv] = sum;
    if (tid == 0) selCount = 0;
    __syncthreads();
    float inv = 1.f / (rbuf[4] + rbuf[5] + rbuf[6] + rbuf[7]);

    if (tid < 64) {
        int s = c0 + tid;
        int idx = b * S_ + s;
        float sc = mask_at(mask, isByte, idx) ? -__builtin_inff() : sr[s];
        float p = __expf(sc - mx) * inv;
        attn[idx] = p;
        if (p > 1e-9f) {
            int k = atomicAdd(&selCount, 1);
            selIdx[k] = s;
            selW[k]  = p;
        }
    }
    __syncthreads();

    int cnt = selCount;
    if (cnt == 0) return;

    const float* cb = context + (size_t)b * S_ * DIN;
    const int p  = tid >> 7;            // 0 or 1
    const int hb = (tid & 127) * 4;     // h-base: 0..508
    float4 aE = {0.f, 0.f, 0.f, 0.f};
    float4 aO = {0.f, 0.f, 0.f, 0.f};
    int i = p;
    for (; i + 2 < cnt; i += 4) {
        const float* r0 = cb + (size_t)selIdx[i]     * DIN + hb;
        const float* r1 = cb + (size_t)selIdx[i + 2] * DIN + hb;
        float w0 = selW[i], w1 = selW[i + 2];
        float4 v0 = *(const float4*)r0;
        float4 v1 = *(const float4*)r1;
        aE.x += w0 * v0.x; aE.y += w0 * v0.y; aE.z += w0 * v0.z; aE.w += w0 * v0.w;
        aO.x += w1 * v1.x; aO.y += w1 * v1.y; aO.z += w1 * v1.z; aO.w += w1 * v1.w;
    }
    for (; i < cnt; i += 2) {
        const float* r0 = cb + (size_t)selIdx[i] * DIN + hb;
        float w0 = selW[i];
        float4 v0 = *(const float4*)r0;
        aE.x += w0 * v0.x; aE.y += w0 * v0.y; aE.z += w0 * v0.z; aE.w += w0 * v0.w;
    }
    aE.x += aO.x; aE.y += aO.y; aE.z += aO.z; aE.w += aO.w;
    *(float4*)&sh[p * 512 + hb] = aE;
    __syncthreads();

    {
        float v0 = sh[tid]       + sh[512 + tid];
        float v1 = sh[tid + 256] + sh[768 + tid];
        atomicAdd(&wsum[b * DIN + tid],       v0);
        atomicAdd(&wsum[b * DIN + tid + 256], v1);
    }
}

// ---------------- hidden = W_ctx @ wsum + b_ctx ----------------
__global__ __launch_bounds__(256)
void hidden_kernel(const float* __restrict__ W_ctx,
                   const float* __restrict__ b_ctx,
                   const float* __restrict__ wsum,
                   float* __restrict__ hidden) {
    int b = blockIdx.x >> 1;
    int tid = threadIdx.x;
    int h = ((blockIdx.x & 1) << 8) + tid;
    __shared__ float wrow[DIN];
    wrow[tid]       = wsum[b * DIN + tid];
    wrow[tid + 256] = wsum[b * DIN + tid + 256];
    __syncthreads();
    const float* wr = W_ctx + (size_t)h * DIN;
    float acc = 0.f;
    for (int k = 0; k < DIN; k += 4) {
        float4 w4 = *(const float4*)(wr + k);
        acc += w4.x * wrow[k] + w4.y * wrow[k + 1]
             + w4.z * wrow[k + 2] + w4.w * wrow[k + 3];
    }
    hidden[b * DH + h] = acc + b_ctx[h];
}

extern "C" void kernel_launch(void* const* d_in, const int* in_sizes, int n_in,
                              void* d_out, int out_size, void* d_ws, size_t ws_size,
                              hipStream_t stream) {
    const float* input   = (const float*)d_in[0];
    const float* context = (const float*)d_in[1];
    const void*  mask    = d_in[2];
    const float* W_in    = (const float*)d_in[3];
    const float* b_in    = (const float*)d_in[4];
    const float* W_ctx   = (const float*)d_in[5];
    const float* b_ctx   = (const float*)d_in[6];
    const float* v       = (const float*)d_in[7];

    char* ws = (char*)d_ws;
    _Float16* W16   = (_Float16*)ws;
    float* addv     = (float*)(ws + 524288);
    float* scores   = (float*)(ws + 557056);
    float* wsum     = (float*)(ws + 819200);
    int*   maskflag = (int*)(ws + 851968);

    float* hidden = (float*)d_out;                  // [16,512]
    float* attn   = (float*)d_out + B_ * DH;        // [16,4096]

    prep_kernel<<<291, 256, 0, stream>>>(input, W_in, b_in, W_ctx, b_ctx, mask,
                                         W16, addv, wsum, maskflag);
    score_kernel<<<1024, 512, 0, stream>>>(context, W16, addv, v, scores);
    attnwsum_kernel<<<B_ * 64, 256, 0, stream>>>(scores, context, mask, maskflag,
                                                 attn, wsum);
    hidden_kernel<<<B_ * 2, 256, 0, stream>>>(W_ctx, b_ctx, wsum, hidden);
}